// Round 7
// baseline (736.825 us; speedup 1.0000x reference)
//
#include <hip/hip_runtime.h>
#include <hip/hip_cooperative_groups.h>

namespace cg = cooperative_groups;

#define D 128

typedef __bf16 bf16x8 __attribute__((ext_vector_type(8)));
typedef float f32x4 __attribute__((ext_vector_type(4)));

__device__ __forceinline__ ushort f2bf(float f) {
    uint u = __float_as_uint(f);
    uint r = (u + 0x7FFFu + ((u >> 16) & 1u)) >> 16;
    return (ushort)r;
}

// ---------------- cooperative CSR + prep mega-kernel ----------------
// Phases (grid.sync between): zero cnt | hist+prep_w+cvt | scanA | scanB | scanC | scatter

struct CsrArgs {
    const int* dst; const int* src; const float* dval;
    int* cnt; int* rank; int* row_start; int* bsum; int2* csr_sd;
    int E; int N;
    const float* W1; const float* W2; ushort* wt; int L;
    const float* attr; ushort* attr_bf; int n4;
};

__global__ __launch_bounds__(256) void k_csr_coop(CsrArgs a) {
    cg::grid_group grid = cg::this_grid();
    int tid = threadIdx.x;
    int gtid = blockIdx.x * 256 + tid;
    int gsz = gridDim.x * 256;

    // phase 0: zero cnt
    for (int i = gtid; i < a.N; i += gsz) a.cnt[i] = 0;
    grid.sync();

    // phase 1: hist (4 edges/thread) + weight transpose + attr cvt (independent work)
    int nE4 = a.E >> 2;
    for (int q = gtid; q < nE4; q += gsz) {
        int i0 = q * 4;
        int4 d4 = *(const int4*)(a.dst + i0);
        int r0 = atomicAdd(&a.cnt[d4.x], 1);
        int r1 = atomicAdd(&a.cnt[d4.y], 1);
        int r2 = atomicAdd(&a.cnt[d4.z], 1);
        int r3 = atomicAdd(&a.cnt[d4.w], 1);
        *(int4*)(a.rank + i0) = make_int4(r0, r1, r2, r3);
    }
    for (int i = nE4 * 4 + gtid; i < a.E; i += gsz)
        a.rank[i] = atomicAdd(&a.cnt[a.dst[i]], 1);
    int wtot = 2 * a.L * D * D;
    for (int idx = gtid; idx < wtot; idx += gsz) {
        int lm = idx >> 14;            // idx / (D*D)
        int rem = idx & (D * D - 1);
        int k = rem >> 7, n = rem & 127;
        const float* W = ((lm & 1) ? a.W2 : a.W1) + (size_t)(lm >> 1) * D * D;
        a.wt[(size_t)lm * D * D + n * D + k] = f2bf(W[rem]);
    }
    for (int i = gtid; i < a.n4; i += gsz) {
        float4 v = ((const float4*)a.attr)[i];
        uint2 p;
        p.x = ((uint)f2bf(v.y) << 16) | (uint)f2bf(v.x);
        p.y = ((uint)f2bf(v.w) << 16) | (uint)f2bf(v.z);
        ((uint2*)a.attr_bf)[i] = p;
    }
    grid.sync();

    // phase 2: scanA — block b handles nodes [b*1024, b*1024+1024)
    int nb = (a.N + 1023) >> 10;
    __shared__ int sd[256];
    int v0 = 0, v1 = 0, v2 = 0, v3 = 0;
    if (blockIdx.x < nb) {
        int base = blockIdx.x * 1024 + tid * 4;
        if (base + 0 < a.N) v0 = a.cnt[base + 0];
        if (base + 1 < a.N) v1 = a.cnt[base + 1];
        if (base + 2 < a.N) v2 = a.cnt[base + 2];
        if (base + 3 < a.N) v3 = a.cnt[base + 3];
        int s = v0 + v1 + v2 + v3;
        sd[tid] = s;
        __syncthreads();
        for (int off = 1; off < 256; off <<= 1) {
            int t = (tid >= off) ? sd[tid - off] : 0;
            __syncthreads();
            sd[tid] += t;
            __syncthreads();
        }
        if (tid == 255) a.bsum[blockIdx.x] = sd[255];
        int run = sd[tid] - s;
        if (base + 0 < a.N) a.row_start[base + 0] = run; run += v0;
        if (base + 1 < a.N) a.row_start[base + 1] = run; run += v1;
        if (base + 2 < a.N) a.row_start[base + 2] = run; run += v2;
        if (base + 3 < a.N) a.row_start[base + 3] = run;
    }
    grid.sync();

    // phase 3: scanB — one wave of block 0 (nb <= 64)
    if (blockIdx.x == 0 && tid < 64) {
        int v = (tid < nb) ? a.bsum[tid] : 0;
        int orig = v;
        #pragma unroll
        for (int off = 1; off < 64; off <<= 1) {
            int t = __shfl_up(v, off);
            if (tid >= off) v += t;
        }
        if (tid < nb) a.bsum[tid] = v - orig;
    }
    grid.sync();

    // phase 4: scanC
    if (blockIdx.x < nb) {
        int add = a.bsum[blockIdx.x];
        int base = blockIdx.x * 1024 + tid * 4;
        #pragma unroll
        for (int i = 0; i < 4; ++i) {
            int idx = base + i;
            if (idx < a.N) a.row_start[idx] += add;
        }
    }
    if (gtid == 0) a.row_start[a.N] = a.E;
    grid.sync();

    // phase 5: scatter (no atomics)
    for (int q = gtid; q < nE4; q += gsz) {
        int i0 = q * 4;
        int4 d4 = *(const int4*)(a.dst + i0);
        int4 s4 = *(const int4*)(a.src + i0);
        int4 r4 = *(const int4*)(a.rank + i0);
        float4 v4 = *(const float4*)(a.dval + i0);
        a.csr_sd[a.row_start[d4.x] + r4.x] = make_int2(s4.x, __float_as_int(v4.x));
        a.csr_sd[a.row_start[d4.y] + r4.y] = make_int2(s4.y, __float_as_int(v4.y));
        a.csr_sd[a.row_start[d4.z] + r4.z] = make_int2(s4.z, __float_as_int(v4.z));
        a.csr_sd[a.row_start[d4.w] + r4.w] = make_int2(s4.w, __float_as_int(v4.w));
    }
    for (int i = nE4 * 4 + gtid; i < a.E; i += gsz)
        a.csr_sd[a.row_start[a.dst[i]] + a.rank[i]] = make_int2(a.src[i], __float_as_int(a.dval[i]));
}

// ---------------- fused dual GEMM via MFMA ----------------
// 512 threads = 8 waves, 128 rows/block. Both 128x128 bf16 weight mats staged to LDS
// (64KB) via global_load_lds with PRE-SWIZZLED global source (LDS dest linear).
// LDS semantic: lds[r][x] holds wt[r][x ^ (r&7)] (16B granules), so reads XOR with (r&7).

__global__ __launch_bounds__(512) void k_dual_gemm_mfma(
    const ushort* __restrict__ hb, const ushort* __restrict__ wt_layer,
    const float* __restrict__ Wa,
    ushort* __restrict__ z, ushort* __restrict__ zi,
    float* __restrict__ a_src, float* __restrict__ a_dst, int N)
{
    __shared__ ushort sw[2 * 128 * 128];   // 65536 B
    int tid = threadIdx.x;

    #pragma unroll
    for (int it = 0; it < 8; ++it) {
        int chunk = it * 512 + tid;            // 0..4095
        int r = chunk >> 4, x = chunk & 15;
        const char* g = (const char*)wt_layer + (size_t)r * 256 + ((x ^ (r & 7)) << 4);
        __builtin_amdgcn_global_load_lds(
            (const __attribute__((address_space(1))) uint*)g,
            (__attribute__((address_space(3))) uint*)((char*)sw + (size_t)chunk * 16),
            16, 0, 0);
    }

    int wv = tid >> 6, lane = tid & 63;
    int lm = lane & 15, kg = lane >> 4;
    int row0 = blockIdx.x * 128 + wv * 16;
    int arow = row0 + lm;
    if (arow >= N) arow = N - 1;

    bf16x8 af[4];
    #pragma unroll
    for (int k0 = 0; k0 < 4; ++k0)
        af[k0] = *(const bf16x8*)(hb + (size_t)arow * D + k0 * 32 + kg * 8);

    asm volatile("s_waitcnt vmcnt(0)");
    __syncthreads();

    #pragma unroll
    for (int mat = 0; mat < 2; ++mat) {
        f32x4 acc[8];
        #pragma unroll
        for (int ct = 0; ct < 8; ++ct) acc[ct] = (f32x4){0.f, 0.f, 0.f, 0.f};

        #pragma unroll
        for (int ct = 0; ct < 8; ++ct) {
            int r = mat * 128 + ct * 16 + lm;
            const char* base = (const char*)sw + r * 256;
            int sx = (r & 7) << 4;
            #pragma unroll
            for (int k0 = 0; k0 < 4; ++k0) {
                bf16x8 bfr = *(const bf16x8*)(base + ((k0 * 64 + kg * 16) ^ sx));
                acc[ct] = __builtin_amdgcn_mfma_f32_16x16x32_bf16(af[k0], bfr, acc[ct], 0, 0, 0);
            }
        }

        ushort* __restrict__ outp = mat ? zi : z;
        // C layout: col=lane&15 (= lm), row=kg*4+reg
        #pragma unroll
        for (int ct = 0; ct < 8; ++ct)
            #pragma unroll
            for (int rr = 0; rr < 4; ++rr) {
                int row = row0 + kg * 4 + rr;
                if (row < N) outp[(size_t)row * D + ct * 16 + lm] = f2bf(acc[ct][rr]);
            }

        if (mat == 0) {
            #pragma unroll
            for (int rr = 0; rr < 4; ++rr) {
                float pa = 0.f, pb = 0.f;
                #pragma unroll
                for (int ct = 0; ct < 8; ++ct) {
                    float v = acc[ct][rr];
                    pa = fmaf(v, Wa[ct * 16 + lm], pa);
                    pb = fmaf(v, Wa[D + ct * 16 + lm], pb);
                }
                #pragma unroll
                for (int m = 1; m < 16; m <<= 1) { pa += __shfl_xor(pa, m); pb += __shfl_xor(pb, m); }
                if (lm == 0) {
                    int row = row0 + kg * 4 + rr;
                    if (row < N) { a_src[row] = pa; a_dst[row] = pb; }
                }
            }
        }
    }
}

// ---------------- edge kernel: 4 edge slots x 16 channel lanes, 2x manual unroll ----------------

__global__ __launch_bounds__(256) void k_edge(
    const int* __restrict__ row_start, const int2* __restrict__ csr_sd,
    const ushort* __restrict__ z, const ushort* __restrict__ zi,
    const float* __restrict__ a_src, const float* __restrict__ a_dst,
    const float* __restrict__ W0l, const float* __restrict__ Wal,
    ushort* __restrict__ out_bf, float* __restrict__ out_f32, int N)
{
    int node = (blockIdx.x * 256 + threadIdx.x) >> 6;
    int lane = threadIdx.x & 63;
    if (node >= N) return;

    float c0 = W0l[0] * Wal[2 * D];
    int rs = row_start[node];
    int deg = row_start[node + 1] - rs;
    float adst = a_dst[node];
    int cl = lane & 15, es = lane >> 4;

    float acc[8] = {0.f, 0.f, 0.f, 0.f, 0.f, 0.f, 0.f, 0.f};
    float dsum = 0.f;

    for (int base = 0; base < deg; base += 8) {
        int j0 = base + es, j1 = base + 4 + es;
        bool valid0 = j0 < deg, valid1 = j1 < deg;
        int2 sd0 = csr_sd[rs + (valid0 ? j0 : 0)];
        int2 sd1 = csr_sd[rs + (valid1 ? j1 : 0)];
        float e0 = a_src[sd0.x] + adst + __int_as_float(sd0.y) * c0;
        float e1 = a_src[sd1.x] + adst + __int_as_float(sd1.y) * c0;
        e0 = e0 > 0.f ? e0 : 0.01f * e0;
        e1 = e1 > 0.f ? e1 : 0.01f * e1;
        float ex0 = valid0 ? __expf(e0) : 0.f;  // no max-shift: softmax shift-invariant, logits O(10)
        float ex1 = valid1 ? __expf(e1) : 0.f;
        dsum += ex0 + ex1;                       // each edge counted by 16 lanes -> scale by 16 later
        uint4 zv0 = *(const uint4*)(z + (size_t)sd0.x * D + cl * 8);
        uint4 zv1 = *(const uint4*)(z + (size_t)sd1.x * D + cl * 8);
        acc[0] = fmaf(ex0, __uint_as_float(zv0.x << 16), acc[0]);
        acc[1] = fmaf(ex0, __uint_as_float(zv0.x & 0xFFFF0000u), acc[1]);
        acc[2] = fmaf(ex0, __uint_as_float(zv0.y << 16), acc[2]);
        acc[3] = fmaf(ex0, __uint_as_float(zv0.y & 0xFFFF0000u), acc[3]);
        acc[4] = fmaf(ex0, __uint_as_float(zv0.z << 16), acc[4]);
        acc[5] = fmaf(ex0, __uint_as_float(zv0.z & 0xFFFF0000u), acc[5]);
        acc[6] = fmaf(ex0, __uint_as_float(zv0.w << 16), acc[6]);
        acc[7] = fmaf(ex0, __uint_as_float(zv0.w & 0xFFFF0000u), acc[7]);
        acc[0] = fmaf(ex1, __uint_as_float(zv1.x << 16), acc[0]);
        acc[1] = fmaf(ex1, __uint_as_float(zv1.x & 0xFFFF0000u), acc[1]);
        acc[2] = fmaf(ex1, __uint_as_float(zv1.y << 16), acc[2]);
        acc[3] = fmaf(ex1, __uint_as_float(zv1.y & 0xFFFF0000u), acc[3]);
        acc[4] = fmaf(ex1, __uint_as_float(zv1.z << 16), acc[4]);
        acc[5] = fmaf(ex1, __uint_as_float(zv1.z & 0xFFFF0000u), acc[5]);
        acc[6] = fmaf(ex1, __uint_as_float(zv1.w << 16), acc[6]);
        acc[7] = fmaf(ex1, __uint_as_float(zv1.w & 0xFFFF0000u), acc[7]);
    }

    #pragma unroll
    for (int m = 1; m < 64; m <<= 1) dsum += __shfl_xor(dsum, m);
    float inv = (deg > 0) ? 16.0f / dsum : 0.f;

    #pragma unroll
    for (int i = 0; i < 8; ++i) {
        acc[i] += __shfl_xor(acc[i], 16);
        acc[i] += __shfl_xor(acc[i], 32);
    }

    if (es == 0) {
        uint4 zr = *(const uint4*)(zi + (size_t)node * D + cl * 8);
        float zi0 = __uint_as_float(zr.x << 16),         zi1 = __uint_as_float(zr.x & 0xFFFF0000u);
        float zi2 = __uint_as_float(zr.y << 16),         zi3 = __uint_as_float(zr.y & 0xFFFF0000u);
        float zi4 = __uint_as_float(zr.z << 16),         zi5 = __uint_as_float(zr.z & 0xFFFF0000u);
        float zi6 = __uint_as_float(zr.w << 16),         zi7 = __uint_as_float(zr.w & 0xFFFF0000u);
        float o0 = fmaxf(fmaf(acc[0], inv, zi0), 0.f);
        float o1 = fmaxf(fmaf(acc[1], inv, zi1), 0.f);
        float o2 = fmaxf(fmaf(acc[2], inv, zi2), 0.f);
        float o3 = fmaxf(fmaf(acc[3], inv, zi3), 0.f);
        float o4 = fmaxf(fmaf(acc[4], inv, zi4), 0.f);
        float o5 = fmaxf(fmaf(acc[5], inv, zi5), 0.f);
        float o6 = fmaxf(fmaf(acc[6], inv, zi6), 0.f);
        float o7 = fmaxf(fmaf(acc[7], inv, zi7), 0.f);
        if (out_f32) {
            float4* op = (float4*)(out_f32 + (size_t)node * D + cl * 8);
            op[0] = make_float4(o0, o1, o2, o3);
            op[1] = make_float4(o4, o5, o6, o7);
        } else {
            uint4 o;
            o.x = ((uint)f2bf(o1) << 16) | (uint)f2bf(o0);
            o.y = ((uint)f2bf(o3) << 16) | (uint)f2bf(o2);
            o.z = ((uint)f2bf(o5) << 16) | (uint)f2bf(o4);
            o.w = ((uint)f2bf(o7) << 16) | (uint)f2bf(o6);
            *(uint4*)(out_bf + (size_t)node * D + cl * 8) = o;
        }
    }
}

// ---------------- host launch ----------------

extern "C" void kernel_launch(void* const* d_in, const int* in_sizes, int n_in,
                              void* d_out, int out_size, void* d_ws, size_t ws_size,
                              hipStream_t stream) {
    const float* attr = (const float*)d_in[0];
    const float* dval = (const float*)d_in[1];
    const int*   src  = (const int*)d_in[2];
    const int*   dst  = (const int*)d_in[3];
    const float* W0   = (const float*)d_in[4];
    const float* W1   = (const float*)d_in[5];
    const float* W2   = (const float*)d_in[6];
    const float* Wa   = (const float*)d_in[7];

    int N = in_sizes[0] / D;
    int E = in_sizes[2];
    int L = in_sizes[4];

    char* ws = (char*)d_ws;
    size_t off = 0;
    auto alloc = [&](size_t bytes) -> void* {
        void* p = ws + off;
        off = (off + bytes + 255) & ~(size_t)255;
        return p;
    };
    int*    row_start = (int*)alloc((size_t)(N + 1) * 4);
    int*    cnt       = (int*)alloc((size_t)N * 4);
    int*    bsum      = (int*)alloc(4096);
    int*    rank      = (int*)alloc((size_t)E * 4);
    int2*   csr_sd    = (int2*)alloc((size_t)E * 8);
    ushort* zbuf      = (ushort*)alloc((size_t)N * D * 2);
    ushort* zibuf     = (ushort*)alloc((size_t)N * D * 2);
    float*  a_src     = (float*)alloc((size_t)N * 4);
    float*  a_dst     = (float*)alloc((size_t)N * 4);
    ushort* hA        = (ushort*)alloc((size_t)N * D * 2);
    ushort* hB        = (ushort*)alloc((size_t)N * D * 2);
    ushort* attr_bf   = (ushort*)alloc((size_t)N * D * 2);
    ushort* wt        = (ushort*)alloc((size_t)L * 2 * D * D * 2);

    // single cooperative kernel: zero + hist + prep + scan + scatter
    CsrArgs args;
    args.dst = dst; args.src = src; args.dval = dval;
    args.cnt = cnt; args.rank = rank; args.row_start = row_start;
    args.bsum = bsum; args.csr_sd = csr_sd;
    args.E = E; args.N = N;
    args.W1 = W1; args.W2 = W2; args.wt = wt; args.L = L;
    args.attr = attr; args.attr_bf = attr_bf; args.n4 = N * D / 4;
    void* kargs[] = { &args };
    hipLaunchCooperativeKernel((void*)k_csr_coop, dim3(1024), dim3(256), kargs, 0, stream);

    float* outp = (float*)d_out;
    const ushort* h_in = attr_bf;
    for (int l = 0; l < L; ++l) {
        const ushort* wt_layer = wt + (size_t)l * 2 * D * D;
        const float*  Wal  = Wa + (size_t)l * (2 * D + 1);
        const float*  W0l  = W0 + l;

        k_dual_gemm_mfma<<<(N + 127) / 128, 512, 0, stream>>>(h_in, wt_layer, Wal,
                                                              zbuf, zibuf, a_src, a_dst, N);

        ushort* hout_bf  = (l == L - 1) ? nullptr : ((l & 1) == 0 ? hA : hB);
        float*  hout_f32 = (l == L - 1) ? outp : nullptr;
        int nblk = (N * 64 + 255) / 256;
        k_edge<<<nblk, 256, 0, stream>>>(row_start, csr_sd, zbuf, zibuf,
                                         a_src, a_dst, W0l, Wal, hout_bf, hout_f32, N);
        h_in = (l & 1) == 0 ? hA : hB;
    }
}

// Round 8
// 195.597 us; speedup vs baseline: 3.7671x; 3.7671x over previous
//
#include <hip/hip_runtime.h>

#define D 128

typedef __bf16 bf16x8 __attribute__((ext_vector_type(8)));
typedef float f32x4 __attribute__((ext_vector_type(4)));

__device__ __forceinline__ ushort f2bf(float f) {
    uint u = __float_as_uint(f);
    uint r = (u + 0x7FFFu + ((u >> 16) & 1u)) >> 16;
    return (ushort)r;
}

// ---------------- fused prep: zero cnt + weight transpose + attr cvt ----------------
// Block ranges: [0, ZB) zero cnt, [ZB, ZB+2L) prep_w, [ZB+2L, ...) cvt.

__global__ __launch_bounds__(256) void k_prep(
    int* __restrict__ cnt, int N,
    const float* __restrict__ W1, const float* __restrict__ W2, ushort* __restrict__ wt, int L,
    const float* __restrict__ attr, ushort* __restrict__ attr_bf, int n4, int ZB)
{
    int b = blockIdx.x;
    if (b < ZB) {
        int i0 = (b * 256 + threadIdx.x) * 4;
        if (i0 + 3 < N) *(int4*)(cnt + i0) = make_int4(0, 0, 0, 0);
        else for (int i = i0; i < N; ++i) cnt[i] = 0;
    } else if (b < ZB + 2 * L) {
        int bb = b - ZB;
        int l = bb >> 1, m = bb & 1;
        const float* W = (m ? W2 : W1) + (size_t)l * D * D;          // [k][n]
        ushort* o = wt + (size_t)l * 2 * D * D + (size_t)m * D * D;  // [n][k]
        for (int idx = threadIdx.x; idx < D * D; idx += 256) {
            int k = idx >> 7, n = idx & 127;
            o[n * D + k] = f2bf(W[idx]);
        }
    } else {
        int i = (b - ZB - 2 * L) * 256 + threadIdx.x;
        if (i < n4) {
            float4 v = ((const float4*)attr)[i];
            uint2 p;
            p.x = ((uint)f2bf(v.y) << 16) | (uint)f2bf(v.x);
            p.y = ((uint)f2bf(v.w) << 16) | (uint)f2bf(v.z);
            ((uint2*)attr_bf)[i] = p;
        }
    }
}

// ---------------- CSR construction ----------------

// histogram with per-edge rank; 4 edges/thread for memory-level parallelism
__global__ __launch_bounds__(256) void k_hist(const int* __restrict__ dst, int* __restrict__ cnt,
                                              int* __restrict__ rank, int E) {
    int i0 = (blockIdx.x * 256 + threadIdx.x) * 4;
    if (i0 + 3 < E) {
        int4 d4 = *(const int4*)(dst + i0);
        int r0 = atomicAdd(&cnt[d4.x], 1);
        int r1 = atomicAdd(&cnt[d4.y], 1);
        int r2 = atomicAdd(&cnt[d4.z], 1);
        int r3 = atomicAdd(&cnt[d4.w], 1);
        *(int4*)(rank + i0) = make_int4(r0, r1, r2, r3);
    } else {
        for (int i = i0; i < E; ++i) rank[i] = atomicAdd(&cnt[dst[i]], 1);
    }
}

// block-local exclusive scan (wave shfl + 1 barrier); bsum[b] = block total
__global__ __launch_bounds__(256) void k_scanA(const int* __restrict__ cnt, int* __restrict__ row_start,
                                               int* __restrict__ bsum, int N) {
    __shared__ int wtot[4];
    int tid = threadIdx.x, wv = tid >> 6, ln = tid & 63;
    int base = blockIdx.x * 1024 + tid * 4;
    int4 v = make_int4(0, 0, 0, 0);
    if (base + 3 < N) v = *(const int4*)(cnt + base);
    else {
        if (base + 0 < N) v.x = cnt[base + 0];
        if (base + 1 < N) v.y = cnt[base + 1];
        if (base + 2 < N) v.z = cnt[base + 2];
    }
    int s = v.x + v.y + v.z + v.w;
    int incl = s;
    #pragma unroll
    for (int o = 1; o < 64; o <<= 1) { int t = __shfl_up(incl, o); if (ln >= o) incl += t; }
    if (ln == 63) wtot[wv] = incl;
    __syncthreads();
    int woff = 0;
    #pragma unroll
    for (int w = 0; w < 4; ++w) if (w < wv) woff += wtot[w];
    int run = woff + incl - s;
    if (base + 0 < N) row_start[base + 0] = run; run += v.x;
    if (base + 1 < N) row_start[base + 1] = run; run += v.y;
    if (base + 2 < N) row_start[base + 2] = run; run += v.z;
    if (base + 3 < N) row_start[base + 3] = run;
    if (tid == 255) bsum[blockIdx.x] = woff + incl;
}

// adds prefix of bsum (computed redundantly per block, 1 wave) to row_start
__global__ __launch_bounds__(256) void k_scanC(int* __restrict__ row_start,
                                               const int* __restrict__ bsum, int N, int E, int nb) {
    __shared__ int addsh;
    int tid = threadIdx.x;
    if (tid < 64) {
        int v = 0;
        int lim = blockIdx.x < nb ? blockIdx.x : nb;
        for (int j = tid; j < lim; j += 64) v += bsum[j];
        #pragma unroll
        for (int m = 32; m >= 1; m >>= 1) v += __shfl_xor(v, m);
        if (tid == 0) addsh = v;
    }
    __syncthreads();
    int add = addsh;
    int base = blockIdx.x * 1024 + tid * 4;
    if (base + 3 < N) {
        int4 r = *(const int4*)(row_start + base);
        r.x += add; r.y += add; r.z += add; r.w += add;
        *(int4*)(row_start + base) = r;
    } else {
        for (int i = base; i < N; ++i) row_start[i] += add;
    }
    if (blockIdx.x == 0 && tid == 0) row_start[N] = E;
}

// no atomics: pos = row_start[dst] + rank; 4 edges/thread, single packed 8B store each
__global__ __launch_bounds__(256) void k_scatter(const int* __restrict__ src, const int* __restrict__ dst,
                                                 const float* __restrict__ dval,
                                                 const int* __restrict__ row_start, const int* __restrict__ rank,
                                                 int2* __restrict__ csr_sd, int E) {
    int i0 = (blockIdx.x * 256 + threadIdx.x) * 4;
    if (i0 + 3 < E) {
        int4 d4 = *(const int4*)(dst + i0);
        int4 s4 = *(const int4*)(src + i0);
        int4 r4 = *(const int4*)(rank + i0);
        float4 v4 = *(const float4*)(dval + i0);
        csr_sd[row_start[d4.x] + r4.x] = make_int2(s4.x, __float_as_int(v4.x));
        csr_sd[row_start[d4.y] + r4.y] = make_int2(s4.y, __float_as_int(v4.y));
        csr_sd[row_start[d4.z] + r4.z] = make_int2(s4.z, __float_as_int(v4.z));
        csr_sd[row_start[d4.w] + r4.w] = make_int2(s4.w, __float_as_int(v4.w));
    } else {
        for (int i = i0; i < E; ++i)
            csr_sd[row_start[dst[i]] + rank[i]] = make_int2(src[i], __float_as_int(dval[i]));
    }
}

// ---------------- fused dual GEMM via MFMA ----------------
// 512 threads = 8 waves, 128 rows/block. Both 128x128 bf16 weight mats staged to LDS
// (64KB) via global_load_lds with PRE-SWIZZLED global source (LDS dest linear).
// LDS semantic: lds[r][x] holds wt[r][x ^ (r&7)] (16B granules), so reads XOR with (r&7).

__global__ __launch_bounds__(512) void k_dual_gemm_mfma(
    const ushort* __restrict__ hb, const ushort* __restrict__ wt_layer,
    const float* __restrict__ Wa,
    ushort* __restrict__ z, ushort* __restrict__ zi,
    float* __restrict__ a_src, float* __restrict__ a_dst, int N)
{
    __shared__ ushort sw[2 * 128 * 128];   // 65536 B
    int tid = threadIdx.x;

    #pragma unroll
    for (int it = 0; it < 8; ++it) {
        int chunk = it * 512 + tid;            // 0..4095
        int r = chunk >> 4, x = chunk & 15;
        const char* g = (const char*)wt_layer + (size_t)r * 256 + ((x ^ (r & 7)) << 4);
        __builtin_amdgcn_global_load_lds(
            (const __attribute__((address_space(1))) uint*)g,
            (__attribute__((address_space(3))) uint*)((char*)sw + (size_t)chunk * 16),
            16, 0, 0);
    }

    int wv = tid >> 6, lane = tid & 63;
    int lm = lane & 15, kg = lane >> 4;
    int row0 = blockIdx.x * 128 + wv * 16;
    int arow = row0 + lm;
    if (arow >= N) arow = N - 1;

    bf16x8 af[4];
    #pragma unroll
    for (int k0 = 0; k0 < 4; ++k0)
        af[k0] = *(const bf16x8*)(hb + (size_t)arow * D + k0 * 32 + kg * 8);

    asm volatile("s_waitcnt vmcnt(0)");
    __syncthreads();

    #pragma unroll
    for (int mat = 0; mat < 2; ++mat) {
        f32x4 acc[8];
        #pragma unroll
        for (int ct = 0; ct < 8; ++ct) acc[ct] = (f32x4){0.f, 0.f, 0.f, 0.f};

        #pragma unroll
        for (int ct = 0; ct < 8; ++ct) {
            int r = mat * 128 + ct * 16 + lm;
            const char* base = (const char*)sw + r * 256;
            int sx = (r & 7) << 4;
            #pragma unroll
            for (int k0 = 0; k0 < 4; ++k0) {
                bf16x8 bfr = *(const bf16x8*)(base + ((k0 * 64 + kg * 16) ^ sx));
                acc[ct] = __builtin_amdgcn_mfma_f32_16x16x32_bf16(af[k0], bfr, acc[ct], 0, 0, 0);
            }
        }

        ushort* __restrict__ outp = mat ? zi : z;
        // C layout: col=lane&15 (= lm), row=kg*4+reg
        #pragma unroll
        for (int ct = 0; ct < 8; ++ct)
            #pragma unroll
            for (int rr = 0; rr < 4; ++rr) {
                int row = row0 + kg * 4 + rr;
                if (row < N) outp[(size_t)row * D + ct * 16 + lm] = f2bf(acc[ct][rr]);
            }

        if (mat == 0) {
            #pragma unroll
            for (int rr = 0; rr < 4; ++rr) {
                float pa = 0.f, pb = 0.f;
                #pragma unroll
                for (int ct = 0; ct < 8; ++ct) {
                    float v = acc[ct][rr];
                    pa = fmaf(v, Wa[ct * 16 + lm], pa);
                    pb = fmaf(v, Wa[D + ct * 16 + lm], pb);
                }
                #pragma unroll
                for (int m = 1; m < 16; m <<= 1) { pa += __shfl_xor(pa, m); pb += __shfl_xor(pb, m); }
                if (lm == 0) {
                    int row = row0 + kg * 4 + rr;
                    if (row < N) { a_src[row] = pa; a_dst[row] = pb; }
                }
            }
        }
    }
}

// ---------------- edge kernel: 4 edge slots x 16 channel lanes, 2x manual unroll ----------------

__global__ __launch_bounds__(256) void k_edge(
    const int* __restrict__ row_start, const int2* __restrict__ csr_sd,
    const ushort* __restrict__ z, const ushort* __restrict__ zi,
    const float* __restrict__ a_src, const float* __restrict__ a_dst,
    const float* __restrict__ W0l, const float* __restrict__ Wal,
    ushort* __restrict__ out_bf, float* __restrict__ out_f32, int N)
{
    int node = (blockIdx.x * 256 + threadIdx.x) >> 6;
    int lane = threadIdx.x & 63;
    if (node >= N) return;

    float c0 = W0l[0] * Wal[2 * D];
    int rs = row_start[node];
    int deg = row_start[node + 1] - rs;
    float adst = a_dst[node];
    int cl = lane & 15, es = lane >> 4;

    float acc[8] = {0.f, 0.f, 0.f, 0.f, 0.f, 0.f, 0.f, 0.f};
    float dsum = 0.f;

    for (int base = 0; base < deg; base += 8) {
        int j0 = base + es, j1 = base + 4 + es;
        bool valid0 = j0 < deg, valid1 = j1 < deg;
        int2 sd0 = csr_sd[rs + (valid0 ? j0 : 0)];
        int2 sd1 = csr_sd[rs + (valid1 ? j1 : 0)];
        float e0 = a_src[sd0.x] + adst + __int_as_float(sd0.y) * c0;
        float e1 = a_src[sd1.x] + adst + __int_as_float(sd1.y) * c0;
        e0 = e0 > 0.f ? e0 : 0.01f * e0;
        e1 = e1 > 0.f ? e1 : 0.01f * e1;
        float ex0 = valid0 ? __expf(e0) : 0.f;  // no max-shift: softmax shift-invariant, logits O(10)
        float ex1 = valid1 ? __expf(e1) : 0.f;
        dsum += ex0 + ex1;                       // each edge counted by 16 lanes -> scale by 16 later
        uint4 zv0 = *(const uint4*)(z + (size_t)sd0.x * D + cl * 8);
        uint4 zv1 = *(const uint4*)(z + (size_t)sd1.x * D + cl * 8);
        acc[0] = fmaf(ex0, __uint_as_float(zv0.x << 16), acc[0]);
        acc[1] = fmaf(ex0, __uint_as_float(zv0.x & 0xFFFF0000u), acc[1]);
        acc[2] = fmaf(ex0, __uint_as_float(zv0.y << 16), acc[2]);
        acc[3] = fmaf(ex0, __uint_as_float(zv0.y & 0xFFFF0000u), acc[3]);
        acc[4] = fmaf(ex0, __uint_as_float(zv0.z << 16), acc[4]);
        acc[5] = fmaf(ex0, __uint_as_float(zv0.z & 0xFFFF0000u), acc[5]);
        acc[6] = fmaf(ex0, __uint_as_float(zv0.w << 16), acc[6]);
        acc[7] = fmaf(ex0, __uint_as_float(zv0.w & 0xFFFF0000u), acc[7]);
        acc[0] = fmaf(ex1, __uint_as_float(zv1.x << 16), acc[0]);
        acc[1] = fmaf(ex1, __uint_as_float(zv1.x & 0xFFFF0000u), acc[1]);
        acc[2] = fmaf(ex1, __uint_as_float(zv1.y << 16), acc[2]);
        acc[3] = fmaf(ex1, __uint_as_float(zv1.y & 0xFFFF0000u), acc[3]);
        acc[4] = fmaf(ex1, __uint_as_float(zv1.z << 16), acc[4]);
        acc[5] = fmaf(ex1, __uint_as_float(zv1.z & 0xFFFF0000u), acc[5]);
        acc[6] = fmaf(ex1, __uint_as_float(zv1.w << 16), acc[6]);
        acc[7] = fmaf(ex1, __uint_as_float(zv1.w & 0xFFFF0000u), acc[7]);
    }

    #pragma unroll
    for (int m = 1; m < 64; m <<= 1) dsum += __shfl_xor(dsum, m);
    float inv = (deg > 0) ? 16.0f / dsum : 0.f;

    #pragma unroll
    for (int i = 0; i < 8; ++i) {
        acc[i] += __shfl_xor(acc[i], 16);
        acc[i] += __shfl_xor(acc[i], 32);
    }

    if (es == 0) {
        uint4 zr = *(const uint4*)(zi + (size_t)node * D + cl * 8);
        float zi0 = __uint_as_float(zr.x << 16),         zi1 = __uint_as_float(zr.x & 0xFFFF0000u);
        float zi2 = __uint_as_float(zr.y << 16),         zi3 = __uint_as_float(zr.y & 0xFFFF0000u);
        float zi4 = __uint_as_float(zr.z << 16),         zi5 = __uint_as_float(zr.z & 0xFFFF0000u);
        float zi6 = __uint_as_float(zr.w << 16),         zi7 = __uint_as_float(zr.w & 0xFFFF0000u);
        float o0 = fmaxf(fmaf(acc[0], inv, zi0), 0.f);
        float o1 = fmaxf(fmaf(acc[1], inv, zi1), 0.f);
        float o2 = fmaxf(fmaf(acc[2], inv, zi2), 0.f);
        float o3 = fmaxf(fmaf(acc[3], inv, zi3), 0.f);
        float o4 = fmaxf(fmaf(acc[4], inv, zi4), 0.f);
        float o5 = fmaxf(fmaf(acc[5], inv, zi5), 0.f);
        float o6 = fmaxf(fmaf(acc[6], inv, zi6), 0.f);
        float o7 = fmaxf(fmaf(acc[7], inv, zi7), 0.f);
        if (out_f32) {
            float4* op = (float4*)(out_f32 + (size_t)node * D + cl * 8);
            op[0] = make_float4(o0, o1, o2, o3);
            op[1] = make_float4(o4, o5, o6, o7);
        } else {
            uint4 o;
            o.x = ((uint)f2bf(o1) << 16) | (uint)f2bf(o0);
            o.y = ((uint)f2bf(o3) << 16) | (uint)f2bf(o2);
            o.z = ((uint)f2bf(o5) << 16) | (uint)f2bf(o4);
            o.w = ((uint)f2bf(o7) << 16) | (uint)f2bf(o6);
            *(uint4*)(out_bf + (size_t)node * D + cl * 8) = o;
        }
    }
}

// ---------------- host launch ----------------

extern "C" void kernel_launch(void* const* d_in, const int* in_sizes, int n_in,
                              void* d_out, int out_size, void* d_ws, size_t ws_size,
                              hipStream_t stream) {
    const float* attr = (const float*)d_in[0];
    const float* dval = (const float*)d_in[1];
    const int*   src  = (const int*)d_in[2];
    const int*   dst  = (const int*)d_in[3];
    const float* W0   = (const float*)d_in[4];
    const float* W1   = (const float*)d_in[5];
    const float* W2   = (const float*)d_in[6];
    const float* Wa   = (const float*)d_in[7];

    int N = in_sizes[0] / D;
    int E = in_sizes[2];
    int L = in_sizes[4];

    char* ws = (char*)d_ws;
    size_t off = 0;
    auto alloc = [&](size_t bytes) -> void* {
        void* p = ws + off;
        off = (off + bytes + 255) & ~(size_t)255;
        return p;
    };
    int*    row_start = (int*)alloc((size_t)(N + 1) * 4);
    int*    cnt       = (int*)alloc((size_t)N * 4);
    int*    bsum      = (int*)alloc(4096);
    int*    rank      = (int*)alloc((size_t)E * 4);
    int2*   csr_sd    = (int2*)alloc((size_t)E * 8);
    ushort* zbuf      = (ushort*)alloc((size_t)N * D * 2);
    ushort* zibuf     = (ushort*)alloc((size_t)N * D * 2);
    float*  a_src     = (float*)alloc((size_t)N * 4);
    float*  a_dst     = (float*)alloc((size_t)N * 4);
    ushort* hA        = (ushort*)alloc((size_t)N * D * 2);
    ushort* hB        = (ushort*)alloc((size_t)N * D * 2);
    ushort* attr_bf   = (ushort*)alloc((size_t)N * D * 2);
    ushort* wt        = (ushort*)alloc((size_t)L * 2 * D * D * 2);

    // fused prep: zero cnt + weight transpose + attr cvt
    int ZB = (N + 1023) / 1024;
    int n4 = N * D / 4;
    int CB = (n4 + 255) / 256;
    k_prep<<<ZB + 2 * L + CB, 256, 0, stream>>>(cnt, N, W1, W2, wt, L, attr, attr_bf, n4, ZB);

    // CSR build
    k_hist<<<(E + 1023) / 1024, 256, 0, stream>>>(dst, cnt, rank, E);
    int nb = (N + 1023) / 1024;
    k_scanA<<<nb, 256, 0, stream>>>(cnt, row_start, bsum, N);
    k_scanC<<<nb, 256, 0, stream>>>(row_start, bsum, N, E, nb);
    k_scatter<<<(E + 1023) / 1024, 256, 0, stream>>>(src, dst, dval, row_start, rank, csr_sd, E);

    float* outp = (float*)d_out;
    const ushort* h_in = attr_bf;
    for (int l = 0; l < L; ++l) {
        const ushort* wt_layer = wt + (size_t)l * 2 * D * D;
        const float*  Wal  = Wa + (size_t)l * (2 * D + 1);
        const float*  W0l  = W0 + l;

        k_dual_gemm_mfma<<<(N + 127) / 128, 512, 0, stream>>>(h_in, wt_layer, Wal,
                                                              zbuf, zibuf, a_src, a_dst, N);

        ushort* hout_bf  = (l == L - 1) ? nullptr : ((l & 1) == 0 ? hA : hB);
        float*  hout_f32 = (l == L - 1) ? outp : nullptr;
        int nblk = (N * 64 + 255) / 256;
        k_edge<<<nblk, 256, 0, stream>>>(row_start, csr_sd, zbuf, zibuf,
                                         a_src, a_dst, W0l, Wal, hout_bf, hout_f32, N);
        h_in = (l & 1) == 0 ? hA : hB;
    }
}

// Round 9
// 185.351 us; speedup vs baseline: 3.9753x; 1.0553x over previous
//
#include <hip/hip_runtime.h>

#define D 128

typedef __bf16 bf16x8 __attribute__((ext_vector_type(8)));
typedef float f32x4 __attribute__((ext_vector_type(4)));

__device__ __forceinline__ ushort f2bf(float f) {
    uint u = __float_as_uint(f);
    uint r = (u + 0x7FFFu + ((u >> 16) & 1u)) >> 16;
    return (ushort)r;
}

// ---------------- fused prep: zero cnt + weight transpose + attr cvt ----------------

__global__ __launch_bounds__(256) void k_prep(
    int* __restrict__ cnt, int N,
    const float* __restrict__ W1, const float* __restrict__ W2, ushort* __restrict__ wt, int L,
    const float* __restrict__ attr, ushort* __restrict__ attr_bf, int n4, int ZB)
{
    int b = blockIdx.x;
    if (b < ZB) {
        int i0 = (b * 256 + threadIdx.x) * 4;
        if (i0 + 3 < N) *(int4*)(cnt + i0) = make_int4(0, 0, 0, 0);
        else for (int i = i0; i < N; ++i) cnt[i] = 0;
    } else if (b < ZB + 2 * L) {
        int bb = b - ZB;
        int l = bb >> 1, m = bb & 1;
        const float* W = (m ? W2 : W1) + (size_t)l * D * D;          // [k][n]
        ushort* o = wt + (size_t)l * 2 * D * D + (size_t)m * D * D;  // [n][k]
        for (int idx = threadIdx.x; idx < D * D; idx += 256) {
            int k = idx >> 7, n = idx & 127;
            o[n * D + k] = f2bf(W[idx]);
        }
    } else {
        int i = (b - ZB - 2 * L) * 256 + threadIdx.x;
        if (i < n4) {
            float4 v = ((const float4*)attr)[i];
            uint2 p;
            p.x = ((uint)f2bf(v.y) << 16) | (uint)f2bf(v.x);
            p.y = ((uint)f2bf(v.w) << 16) | (uint)f2bf(v.z);
            ((uint2*)attr_bf)[i] = p;
        }
    }
}

// ---------------- CSR scan kernels ----------------

// block-local exclusive scan (wave shfl + 1 barrier); bsum[b] = block total
__global__ __launch_bounds__(256) void k_scanA(const int* __restrict__ cnt, int* __restrict__ row_start,
                                               int* __restrict__ bsum, int N) {
    __shared__ int wtot[4];
    int tid = threadIdx.x, wv = tid >> 6, ln = tid & 63;
    int base = blockIdx.x * 1024 + tid * 4;
    int4 v = make_int4(0, 0, 0, 0);
    if (base + 3 < N) v = *(const int4*)(cnt + base);
    else {
        if (base + 0 < N) v.x = cnt[base + 0];
        if (base + 1 < N) v.y = cnt[base + 1];
        if (base + 2 < N) v.z = cnt[base + 2];
    }
    int s = v.x + v.y + v.z + v.w;
    int incl = s;
    #pragma unroll
    for (int o = 1; o < 64; o <<= 1) { int t = __shfl_up(incl, o); if (ln >= o) incl += t; }
    if (ln == 63) wtot[wv] = incl;
    __syncthreads();
    int woff = 0;
    #pragma unroll
    for (int w = 0; w < 4; ++w) if (w < wv) woff += wtot[w];
    int run = woff + incl - s;
    if (base + 0 < N) row_start[base + 0] = run; run += v.x;
    if (base + 1 < N) row_start[base + 1] = run; run += v.y;
    if (base + 2 < N) row_start[base + 2] = run; run += v.z;
    if (base + 3 < N) row_start[base + 3] = run;
    if (tid == 255) bsum[blockIdx.x] = woff + incl;
}

// adds prefix of bsum (computed redundantly per block, 1 wave) to row_start
__global__ __launch_bounds__(256) void k_scanC(int* __restrict__ row_start,
                                               const int* __restrict__ bsum, int N, int E, int nb) {
    __shared__ int addsh;
    int tid = threadIdx.x;
    if (tid < 64) {
        int v = 0;
        int lim = blockIdx.x < nb ? blockIdx.x : nb;
        for (int j = tid; j < lim; j += 64) v += bsum[j];
        #pragma unroll
        for (int m = 32; m >= 1; m >>= 1) v += __shfl_xor(v, m);
        if (tid == 0) addsh = v;
    }
    __syncthreads();
    int add = addsh;
    int base = blockIdx.x * 1024 + tid * 4;
    if (base + 3 < N) {
        int4 r = *(const int4*)(row_start + base);
        r.x += add; r.y += add; r.z += add; r.w += add;
        *(int4*)(row_start + base) = r;
    } else {
        for (int i = base; i < N; ++i) row_start[i] += add;
    }
    if (blockIdx.x == 0 && tid == 0) row_start[N] = E;
}

// no atomics: pos = row_start[dst] + rank; 4 edges/thread, single packed 8B store each
__global__ __launch_bounds__(256) void k_scatter(const int* __restrict__ src, const int* __restrict__ dst,
                                                 const float* __restrict__ dval,
                                                 const int* __restrict__ row_start, const int* __restrict__ rank,
                                                 int2* __restrict__ csr_sd, int E) {
    int i0 = (blockIdx.x * 256 + threadIdx.x) * 4;
    if (i0 + 3 < E) {
        int4 d4 = *(const int4*)(dst + i0);
        int4 s4 = *(const int4*)(src + i0);
        int4 r4 = *(const int4*)(rank + i0);
        float4 v4 = *(const float4*)(dval + i0);
        csr_sd[row_start[d4.x] + r4.x] = make_int2(s4.x, __float_as_int(v4.x));
        csr_sd[row_start[d4.y] + r4.y] = make_int2(s4.y, __float_as_int(v4.y));
        csr_sd[row_start[d4.z] + r4.z] = make_int2(s4.z, __float_as_int(v4.z));
        csr_sd[row_start[d4.w] + r4.w] = make_int2(s4.w, __float_as_int(v4.w));
    } else {
        for (int i = i0; i < E; ++i)
            csr_sd[row_start[dst[i]] + rank[i]] = make_int2(src[i], __float_as_int(dval[i]));
    }
}

// ---------------- fused dual GEMM via MFMA (+ optional hist blocks appended) ----------------
// Blocks [0, NG): 8-wave GEMM over 128 rows. Blocks [NG, NG+HB): histogram, 512thr x 4 edges.
// GEMM: both 128x128 bf16 weight mats staged to LDS (64KB) via global_load_lds with
// PRE-SWIZZLED global source (LDS dest linear); reads XOR with (r&7).

__global__ __launch_bounds__(512) void k_dual_gemm_mfma(
    const ushort* __restrict__ hb, const ushort* __restrict__ wt_layer,
    const float* __restrict__ Wa,
    ushort* __restrict__ z, ushort* __restrict__ zi,
    float* __restrict__ a_src, float* __restrict__ a_dst, int N,
    int NG, const int* __restrict__ dst, int* __restrict__ cnt, int* __restrict__ rank, int E)
{
    __shared__ ushort sw[2 * 128 * 128];   // 65536 B
    int tid = threadIdx.x;

    if (blockIdx.x >= NG) {
        // ---- histogram branch: 4 edges/thread, 4 atomics in flight ----
        int i0 = ((blockIdx.x - NG) * 512 + tid) * 4;
        if (i0 + 3 < E) {
            int4 d4 = *(const int4*)(dst + i0);
            int r0 = atomicAdd(&cnt[d4.x], 1);
            int r1 = atomicAdd(&cnt[d4.y], 1);
            int r2 = atomicAdd(&cnt[d4.z], 1);
            int r3 = atomicAdd(&cnt[d4.w], 1);
            *(int4*)(rank + i0) = make_int4(r0, r1, r2, r3);
        } else {
            for (int i = i0; i < E; ++i) rank[i] = atomicAdd(&cnt[dst[i]], 1);
        }
        return;
    }

    #pragma unroll
    for (int it = 0; it < 8; ++it) {
        int chunk = it * 512 + tid;            // 0..4095
        int r = chunk >> 4, x = chunk & 15;
        const char* g = (const char*)wt_layer + (size_t)r * 256 + ((x ^ (r & 7)) << 4);
        __builtin_amdgcn_global_load_lds(
            (const __attribute__((address_space(1))) uint*)g,
            (__attribute__((address_space(3))) uint*)((char*)sw + (size_t)chunk * 16),
            16, 0, 0);
    }

    int wv = tid >> 6, lane = tid & 63;
    int lm = lane & 15, kg = lane >> 4;
    int row0 = blockIdx.x * 128 + wv * 16;
    int arow = row0 + lm;
    if (arow >= N) arow = N - 1;

    bf16x8 af[4];
    #pragma unroll
    for (int k0 = 0; k0 < 4; ++k0)
        af[k0] = *(const bf16x8*)(hb + (size_t)arow * D + k0 * 32 + kg * 8);

    asm volatile("s_waitcnt vmcnt(0)");
    __syncthreads();

    #pragma unroll
    for (int mat = 0; mat < 2; ++mat) {
        f32x4 acc[8];
        #pragma unroll
        for (int ct = 0; ct < 8; ++ct) acc[ct] = (f32x4){0.f, 0.f, 0.f, 0.f};

        #pragma unroll
        for (int ct = 0; ct < 8; ++ct) {
            int r = mat * 128 + ct * 16 + lm;
            const char* base = (const char*)sw + r * 256;
            int sx = (r & 7) << 4;
            #pragma unroll
            for (int k0 = 0; k0 < 4; ++k0) {
                bf16x8 bfr = *(const bf16x8*)(base + ((k0 * 64 + kg * 16) ^ sx));
                acc[ct] = __builtin_amdgcn_mfma_f32_16x16x32_bf16(af[k0], bfr, acc[ct], 0, 0, 0);
            }
        }

        ushort* __restrict__ outp = mat ? zi : z;
        // C layout: col=lane&15 (= lm), row=kg*4+reg
        #pragma unroll
        for (int ct = 0; ct < 8; ++ct)
            #pragma unroll
            for (int rr = 0; rr < 4; ++rr) {
                int row = row0 + kg * 4 + rr;
                if (row < N) outp[(size_t)row * D + ct * 16 + lm] = f2bf(acc[ct][rr]);
            }

        if (mat == 0) {
            #pragma unroll
            for (int rr = 0; rr < 4; ++rr) {
                float pa = 0.f, pb = 0.f;
                #pragma unroll
                for (int ct = 0; ct < 8; ++ct) {
                    float v = acc[ct][rr];
                    pa = fmaf(v, Wa[ct * 16 + lm], pa);
                    pb = fmaf(v, Wa[D + ct * 16 + lm], pb);
                }
                #pragma unroll
                for (int m = 1; m < 16; m <<= 1) { pa += __shfl_xor(pa, m); pb += __shfl_xor(pb, m); }
                if (lm == 0) {
                    int row = row0 + kg * 4 + rr;
                    if (row < N) { a_src[row] = pa; a_dst[row] = pb; }
                }
            }
        }
    }
}

// ---------------- edge kernel: 4 edge slots x 16 channel lanes, 4x unroll (16 edges/iter) ----------------

__global__ __launch_bounds__(256) void k_edge(
    const int* __restrict__ row_start, const int2* __restrict__ csr_sd,
    const ushort* __restrict__ z, const ushort* __restrict__ zi,
    const float* __restrict__ a_src, const float* __restrict__ a_dst,
    const float* __restrict__ W0l, const float* __restrict__ Wal,
    ushort* __restrict__ out_bf, float* __restrict__ out_f32, int N)
{
    int node = (blockIdx.x * 256 + threadIdx.x) >> 6;
    int lane = threadIdx.x & 63;
    if (node >= N) return;

    float c0 = W0l[0] * Wal[2 * D];
    int rs = row_start[node];
    int deg = row_start[node + 1] - rs;
    float adst = a_dst[node];
    int cl = lane & 15, es = lane >> 4;

    float acc[8] = {0.f, 0.f, 0.f, 0.f, 0.f, 0.f, 0.f, 0.f};
    float dsum = 0.f;

    for (int base = 0; base < deg; base += 16) {
        int2 sd[4];
        float ex[4];
        #pragma unroll
        for (int u = 0; u < 4; ++u) {
            int j = base + u * 4 + es;
            bool valid = j < deg;
            sd[u] = csr_sd[rs + (valid ? j : 0)];
            float e = a_src[sd[u].x] + adst + __int_as_float(sd[u].y) * c0;
            e = e > 0.f ? e : 0.01f * e;
            ex[u] = valid ? __expf(e) : 0.f;  // no max-shift: softmax shift-invariant, logits O(10)
            dsum += ex[u];                     // each edge counted by 16 lanes -> scale by 16 later
        }
        #pragma unroll
        for (int u = 0; u < 4; ++u) {
            uint4 zv = *(const uint4*)(z + (size_t)sd[u].x * D + cl * 8);
            acc[0] = fmaf(ex[u], __uint_as_float(zv.x << 16), acc[0]);
            acc[1] = fmaf(ex[u], __uint_as_float(zv.x & 0xFFFF0000u), acc[1]);
            acc[2] = fmaf(ex[u], __uint_as_float(zv.y << 16), acc[2]);
            acc[3] = fmaf(ex[u], __uint_as_float(zv.y & 0xFFFF0000u), acc[3]);
            acc[4] = fmaf(ex[u], __uint_as_float(zv.z << 16), acc[4]);
            acc[5] = fmaf(ex[u], __uint_as_float(zv.z & 0xFFFF0000u), acc[5]);
            acc[6] = fmaf(ex[u], __uint_as_float(zv.w << 16), acc[6]);
            acc[7] = fmaf(ex[u], __uint_as_float(zv.w & 0xFFFF0000u), acc[7]);
        }
    }

    #pragma unroll
    for (int m = 1; m < 64; m <<= 1) dsum += __shfl_xor(dsum, m);
    float inv = (deg > 0) ? 16.0f / dsum : 0.f;

    #pragma unroll
    for (int i = 0; i < 8; ++i) {
        acc[i] += __shfl_xor(acc[i], 16);
        acc[i] += __shfl_xor(acc[i], 32);
    }

    if (es == 0) {
        uint4 zr = *(const uint4*)(zi + (size_t)node * D + cl * 8);
        float zi0 = __uint_as_float(zr.x << 16),         zi1 = __uint_as_float(zr.x & 0xFFFF0000u);
        float zi2 = __uint_as_float(zr.y << 16),         zi3 = __uint_as_float(zr.y & 0xFFFF0000u);
        float zi4 = __uint_as_float(zr.z << 16),         zi5 = __uint_as_float(zr.z & 0xFFFF0000u);
        float zi6 = __uint_as_float(zr.w << 16),         zi7 = __uint_as_float(zr.w & 0xFFFF0000u);
        float o0 = fmaxf(fmaf(acc[0], inv, zi0), 0.f);
        float o1 = fmaxf(fmaf(acc[1], inv, zi1), 0.f);
        float o2 = fmaxf(fmaf(acc[2], inv, zi2), 0.f);
        float o3 = fmaxf(fmaf(acc[3], inv, zi3), 0.f);
        float o4 = fmaxf(fmaf(acc[4], inv, zi4), 0.f);
        float o5 = fmaxf(fmaf(acc[5], inv, zi5), 0.f);
        float o6 = fmaxf(fmaf(acc[6], inv, zi6), 0.f);
        float o7 = fmaxf(fmaf(acc[7], inv, zi7), 0.f);
        if (out_f32) {
            float4* op = (float4*)(out_f32 + (size_t)node * D + cl * 8);
            op[0] = make_float4(o0, o1, o2, o3);
            op[1] = make_float4(o4, o5, o6, o7);
        } else {
            uint4 o;
            o.x = ((uint)f2bf(o1) << 16) | (uint)f2bf(o0);
            o.y = ((uint)f2bf(o3) << 16) | (uint)f2bf(o2);
            o.z = ((uint)f2bf(o5) << 16) | (uint)f2bf(o4);
            o.w = ((uint)f2bf(o7) << 16) | (uint)f2bf(o6);
            *(uint4*)(out_bf + (size_t)node * D + cl * 8) = o;
        }
    }
}

// ---------------- host launch ----------------

extern "C" void kernel_launch(void* const* d_in, const int* in_sizes, int n_in,
                              void* d_out, int out_size, void* d_ws, size_t ws_size,
                              hipStream_t stream) {
    const float* attr = (const float*)d_in[0];
    const float* dval = (const float*)d_in[1];
    const int*   src  = (const int*)d_in[2];
    const int*   dst  = (const int*)d_in[3];
    const float* W0   = (const float*)d_in[4];
    const float* W1   = (const float*)d_in[5];
    const float* W2   = (const float*)d_in[6];
    const float* Wa   = (const float*)d_in[7];

    int N = in_sizes[0] / D;
    int E = in_sizes[2];
    int L = in_sizes[4];

    char* ws = (char*)d_ws;
    size_t off = 0;
    auto alloc = [&](size_t bytes) -> void* {
        void* p = ws + off;
        off = (off + bytes + 255) & ~(size_t)255;
        return p;
    };
    int*    row_start = (int*)alloc((size_t)(N + 1) * 4);
    int*    cnt       = (int*)alloc((size_t)N * 4);
    int*    bsum      = (int*)alloc(4096);
    int*    rank      = (int*)alloc((size_t)E * 4);
    int2*   csr_sd    = (int2*)alloc((size_t)E * 8);
    ushort* zbuf      = (ushort*)alloc((size_t)N * D * 2);
    ushort* zibuf     = (ushort*)alloc((size_t)N * D * 2);
    float*  a_src     = (float*)alloc((size_t)N * 4);
    float*  a_dst     = (float*)alloc((size_t)N * 4);
    ushort* hA        = (ushort*)alloc((size_t)N * D * 2);
    ushort* hB        = (ushort*)alloc((size_t)N * D * 2);
    ushort* attr_bf   = (ushort*)alloc((size_t)N * D * 2);
    ushort* wt        = (ushort*)alloc((size_t)L * 2 * D * D * 2);

    // fused prep: zero cnt + weight transpose + attr cvt
    int ZB = (N + 1023) / 1024;
    int n4 = N * D / 4;
    int CB = (n4 + 255) / 256;
    k_prep<<<ZB + 2 * L + CB, 256, 0, stream>>>(cnt, N, W1, W2, wt, L, attr, attr_bf, n4, ZB);

    int NG = (N + 127) / 128;
    int HB = (E + 2047) / 2048;
    int nb = (N + 1023) / 1024;

    float* outp = (float*)d_out;
    const ushort* h_in = attr_bf;
    for (int l = 0; l < L; ++l) {
        const ushort* wt_layer = wt + (size_t)l * 2 * D * D;
        const float*  Wal  = Wa + (size_t)l * (2 * D + 1);
        const float*  W0l  = W0 + l;

        // layer 0: append histogram blocks to the GEMM dispatch (independent work)
        int extra = (l == 0) ? HB : 0;
        k_dual_gemm_mfma<<<NG + extra, 512, 0, stream>>>(h_in, wt_layer, Wal,
                                                         zbuf, zibuf, a_src, a_dst, N,
                                                         NG, dst, cnt, rank, E);
        if (l == 0) {
            // CSR scan + scatter (needs hist, which completed with the gemm dispatch)
            k_scanA<<<nb, 256, 0, stream>>>(cnt, row_start, bsum, N);
            k_scanC<<<nb, 256, 0, stream>>>(row_start, bsum, N, E, nb);
            k_scatter<<<(E + 1023) / 1024, 256, 0, stream>>>(src, dst, dval, row_start, rank, csr_sd, E);
        }

        ushort* hout_bf  = (l == L - 1) ? nullptr : ((l & 1) == 0 ? hA : hB);
        float*  hout_f32 = (l == L - 1) ? outp : nullptr;
        int nblk = (N * 64 + 255) / 256;
        k_edge<<<nblk, 256, 0, stream>>>(row_start, csr_sd, zbuf, zibuf,
                                         a_src, a_dst, W0l, Wal, hout_bf, hout_f32, N);
        h_in = (l & 1) == 0 ? hA : hB;
    }
}